// Round 1
// 390.013 us; speedup vs baseline: 1.0159x; 1.0159x over previous
//
#include <hip/hip_runtime.h>
#include <hip/hip_bf16.h>

#define EMB 1024
#define CTX 32
#define NEXP 16
#define H1 2048
#define H2 512
#define NBIG 16384  // F_IN*R == R*F_OUT

typedef __attribute__((ext_vector_type(8))) short short8;
typedef __attribute__((ext_vector_type(4))) float floatx4;
typedef const __attribute__((address_space(1))) void* gas_t;
typedef __attribute__((address_space(3))) void* las_t;

__device__ __forceinline__ void gl16(const unsigned short* g, unsigned short* l) {
  __builtin_amdgcn_global_load_lds((gas_t)(const void*)g, (las_t)(void*)l, 16, 0, 0);
}

__device__ inline unsigned short bf_bits(float x) {
  unsigned u = __builtin_bit_cast(unsigned, x);
  u += 0x7fffu + ((u >> 16) & 1u);  // round-to-nearest-even
  return (unsigned short)(u >> 16);
}
__device__ inline unsigned pk_bf16(float a, float b) {
  return (unsigned)bf_bits(a) | ((unsigned)bf_bits(b) << 16);
}

// ---------------- K1a: g1 = relu(s @ Wg1 + bg1)  (8 x 2048) ----------------
__global__ void __launch_bounds__(256) k_gate1(const float* __restrict__ s,
                                               const float* __restrict__ Wg1,
                                               const float* __restrict__ bg1,
                                               float* __restrict__ g1) {
  __shared__ float red[16][16][8];
  int t = threadIdx.x;
  int c = t & 15, kk = t >> 4;
  int h = blockIdx.x * 16 + c;
  float acc[8];
#pragma unroll
  for (int b = 0; b < 8; ++b) acc[b] = 0.f;
  int k0 = kk * 64;
  for (int k = k0; k < k0 + 64; ++k) {
    float w = Wg1[(size_t)k * H1 + h];
#pragma unroll
    for (int b = 0; b < 8; ++b) acc[b] += s[b * EMB + k] * w;
  }
#pragma unroll
  for (int b = 0; b < 8; ++b) red[kk][c][b] = acc[b];
  __syncthreads();
  if (t < 128) {
    int cc = t >> 3, b = t & 7;
    float v = 0.f;
#pragma unroll
    for (int q = 0; q < 16; ++q) v += red[q][cc][b];
    int hh = blockIdx.x * 16 + cc;
    v += bg1[hh];
    g1[b * H1 + hh] = fmaxf(v, 0.f);
  }
}

// ---------------- K1b: logits = g1 @ Wg2 + bg2  (8 x 16) ----------------
__global__ void __launch_bounds__(256) k_gate2(const float* __restrict__ g1,
                                               const float* __restrict__ Wg2,
                                               const float* __restrict__ bg2,
                                               float* __restrict__ logits) {
  __shared__ float red[256][8];
  int e = blockIdx.x, t = threadIdx.x;
  int k0 = t * 8;
  float wv[8];
#pragma unroll
  for (int j = 0; j < 8; ++j) wv[j] = Wg2[(size_t)(k0 + j) * NEXP + e];
  float acc[8];
#pragma unroll
  for (int b = 0; b < 8; ++b) {
    float4 ga = *(const float4*)&g1[b * H1 + k0];
    float4 gb = *(const float4*)&g1[b * H1 + k0 + 4];
    acc[b] = ga.x * wv[0] + ga.y * wv[1] + ga.z * wv[2] + ga.w * wv[3] +
             gb.x * wv[4] + gb.y * wv[5] + gb.z * wv[6] + gb.w * wv[7];
  }
#pragma unroll
  for (int b = 0; b < 8; ++b) red[t][b] = acc[b];
  __syncthreads();
  for (int off = 128; off > 0; off >>= 1) {
    if (t < off) {
#pragma unroll
      for (int b = 0; b < 8; ++b) red[t][b] += red[t + off][b];
    }
    __syncthreads();
  }
  if (t < 8) logits[t * NEXP + e] = red[0][t] + bg2[e];
}

// ---------------- K2: base[e,b,h] = s @ W1s + b1 ----------------
__global__ void __launch_bounds__(512) k_base(const float* __restrict__ s,
                                              const float* __restrict__ W1,
                                              const float* __restrict__ b1,
                                              float* __restrict__ base) {
  __shared__ float sl[8 * EMB];
  __shared__ float red[8][64][17];
  int t = threadIdx.x;
  int ht = blockIdx.x;
  int e = blockIdx.y;
#pragma unroll
  for (int i = 0; i < 4; ++i) {
    int idx = (t + i * 512) * 4;
    *(float4*)&sl[idx] = *(const float4*)&s[idx];
  }
  __syncthreads();
  int hp = t & 63;
  int kk = t >> 6;
  int h = ht * 128 + hp * 2;
  const float* wp = W1 + (size_t)e * 1056 * H1 + h;
  float a0[8], a1[8];
#pragma unroll
  for (int b = 0; b < 8; ++b) { a0[b] = 0.f; a1[b] = 0.f; }
  int k0 = kk * 128;
  for (int k = k0; k < k0 + 128; ++k) {
    float2 w = *(const float2*)(wp + (size_t)k * H1);
#pragma unroll
    for (int b = 0; b < 8; ++b) {
      float sv = sl[b * EMB + k];
      a0[b] += sv * w.x;
      a1[b] += sv * w.y;
    }
  }
#pragma unroll
  for (int b = 0; b < 8; ++b) {
    red[kk][hp][b * 2] = a0[b];
    red[kk][hp][b * 2 + 1] = a1[b];
  }
  __syncthreads();
  if (t < 64) {
    int hh = ht * 128 + t * 2;
#pragma unroll
    for (int b = 0; b < 8; ++b) {
      float v0 = 0.f, v1 = 0.f;
#pragma unroll
      for (int q = 0; q < 8; ++q) {
        v0 += red[q][t][b * 2];
        v1 += red[q][t][b * 2 + 1];
      }
      float2 bv = *(const float2*)&b1[e * H1 + hh];
      float2 o;
      o.x = v0 + bv.x;
      o.y = v1 + bv.y;
      *(float2*)&base[(size_t)(e * 8 + b) * H1 + hh] = o;
    }
  }
}

// ---- K-packW: fp32 [K][Nsrc] -> tiled-swizzled bf16 [K/64][Ndst][8c][8] ----
// (used only for W2 now). grid (Nsrc/64, K/64, batch), block 256.
__global__ void __launch_bounds__(256) k_packW(const float* __restrict__ src,
                                               unsigned short* __restrict__ dst,
                                               int Nsrc, int Ndst, int n_off,
                                               long sbs, long dbs) {
  __shared__ float tl[64][65];
  int nt = blockIdx.x, kb = blockIdx.y, bz = blockIdx.z, t = threadIdx.x;
  const float* S = src + (size_t)bz * sbs + (size_t)kb * 64 * Nsrc + nt * 64;
  int r = t >> 4, c4 = (t & 15) * 4;
#pragma unroll
  for (int i = 0; i < 4; ++i) {
    int row = r + i * 16;
    float4 v = *(const float4*)&S[(size_t)row * Nsrc + c4];
    *(float4*)&tl[row][c4] = v;
  }
  __syncthreads();
  int nl = t >> 2;
  int cb = (t & 3) * 2;
  int key = nl & 7;
  unsigned short* D = dst + (size_t)bz * dbs +
                      ((size_t)kb * Ndst + n_off + nt * 64 + nl) * 64;
#pragma unroll
  for (int j = 0; j < 2; ++j) {
    int cp = cb + j;
    int k0 = (cp ^ key) * 8;
    union { short8 v; unsigned u[4]; } p;
#pragma unroll
    for (int q = 0; q < 4; ++q)
      p.u[q] = pk_bf16(tl[k0 + 2 * q][nl], tl[k0 + 2 * q + 1][nl]);
    *(short8*)&D[cp * 8] = p.v;
  }
}

// ---- K3: eo2[ks][c,e,b,d] = relu(base+W1c) @ W2  (fused-h A staging) ----
// 256 blocks = mt4 x (e16 x nt2 x ks2); BM=64 BN=256 BK=64; 512 thr, 8 waves.
// id = mt*64 + (e*4 + nt*2 + ks): B-tile sharers (mt varies) are id stride 64
// == 0 mod 8 -> same XCD -> L2 reuse of the 4x B re-read.
__global__ void __launch_bounds__(512) k_egemm2(const float* __restrict__ base,
                                                const float* __restrict__ W1,
                                                const unsigned short* __restrict__ W2t,
                                                float* __restrict__ eo2) {
  __shared__ __align__(16) unsigned short As[4096];    // 64 x 64 (8KB)
  __shared__ __align__(16) unsigned short Bs[16384];   // 256 x 64 (32KB)
  int id = blockIdx.x;
  int mt = id >> 6, rem = id & 63;
  int e = rem >> 2, nt = (rem >> 1) & 1, ks = rem & 1;
  int t = threadIdx.x, lane = t & 63, w = t >> 6;
  int wm = w >> 2, wn = w & 3;        // 2 x 4 wave grid, wave tile 32m x 64n
  int fr = lane & 15, quad = lane >> 4, key = fr & 7;

  // A staging: thread -> (row am 0..63, k-chunk t&7)
  int am = t >> 3;
  int ak = (t & 7) * 8;
  const float* bp = base + ((size_t)e * 8 + (am & 7)) * H1;              // b row
  const float* cp = W1 + ((size_t)e * 1056 + EMB + mt * 8 + (am >> 3)) * H1;  // c row
  unsigned short* adst = &As[am * 64 + (((t & 7) ^ (am & 7)) * 8)];
  const unsigned short* wBe = W2t + (size_t)e * 1048576 + (size_t)nt * 16384;

  floatx4 zero4 = {0.f, 0.f, 0.f, 0.f};
  floatx4 acc[2][4];
#pragma unroll
  for (int i = 0; i < 2; ++i)
#pragma unroll
    for (int j = 0; j < 4; ++j) acc[i][j] = zero4;

  for (int i = 0; i < 16; ++i) {
    int kb = ks * 16 + i;
    __syncthreads();
    // B: async global->LDS (pre-packed bf16, linear dest)
    const unsigned short* bsrc = wBe + (size_t)kb * 32768 + t * 8;
    gl16(bsrc, &Bs[t * 8]);
    gl16(bsrc + 4096, &Bs[t * 8 + 4096]);
    gl16(bsrc + 8192, &Bs[t * 8 + 8192]);
    gl16(bsrc + 12288, &Bs[t * 8 + 12288]);
    // A: fused h = relu(base + W1c) -> bf16, swizzled ds_write (overlaps gl16 flight)
    int k0 = kb * 64 + ak;
    float4 x0 = *(const float4*)&bp[k0];
    float4 x1 = *(const float4*)&bp[k0 + 4];
    float4 y0 = *(const float4*)&cp[k0];
    float4 y1 = *(const float4*)&cp[k0 + 4];
    union { short8 v; unsigned u[4]; } pq;
    pq.u[0] = pk_bf16(fmaxf(x0.x + y0.x, 0.f), fmaxf(x0.y + y0.y, 0.f));
    pq.u[1] = pk_bf16(fmaxf(x0.z + y0.z, 0.f), fmaxf(x0.w + y0.w, 0.f));
    pq.u[2] = pk_bf16(fmaxf(x1.x + y1.x, 0.f), fmaxf(x1.y + y1.y, 0.f));
    pq.u[3] = pk_bf16(fmaxf(x1.z + y1.z, 0.f), fmaxf(x1.w + y1.w, 0.f));
    *(short8*)adst = pq.v;
    __syncthreads();
#pragma unroll
    for (int ks2 = 0; ks2 < 2; ++ks2) {
      int cof = ((ks2 * 4 + quad) ^ key) * 8;
      short8 a0 = *(const short8*)&As[(wm * 32 + fr) * 64 + cof];
      short8 a1 = *(const short8*)&As[(wm * 32 + 16 + fr) * 64 + cof];
#pragma unroll
      for (int nj = 0; nj < 4; ++nj) {
        short8 bf = *(const short8*)&Bs[(wn * 64 + nj * 16 + fr) * 64 + cof];
        acc[0][nj] = __builtin_amdgcn_mfma_f32_16x16x32_bf16(a0, bf, acc[0][nj], 0, 0, 0);
        acc[1][nj] = __builtin_amdgcn_mfma_f32_16x16x32_bf16(a1, bf, acc[1][nj], 0, 0, 0);
      }
    }
  }
  float* op = eo2 + (size_t)ks * 2097152;
  int d0 = nt * 256 + wn * 64 + fr;
#pragma unroll
  for (int nj = 0; nj < 4; ++nj) {
    int d = d0 + nj * 16;
#pragma unroll
    for (int rt = 0; rt < 2; ++rt) {
#pragma unroll
      for (int i2 = 0; i2 < 4; ++i2) {
        int gm = mt * 64 + wm * 32 + rt * 16 + quad * 4 + i2;
        op[(((size_t)(gm >> 3) * NEXP + e) * 8 + (gm & 7)) * H2 + d] = acc[rt][nj][i2];
      }
    }
  }
}

// ---- K4: z_t tiled bf16 = sum_e softmax * (eo2a+eo2b+b2) ----
__global__ void __launch_bounds__(256) k_mix(const float* __restrict__ eo2,
                                             const float* __restrict__ logits,
                                             const float* __restrict__ b2,
                                             unsigned short* __restrict__ z_t) {
  int c = blockIdx.x, half = blockIdx.y, t = threadIdx.x;
  int b = t >> 5;
  int dc = half * 32 + (t & 31);
  int d0 = dc * 8;
  int m = c * 8 + b;
  float lg[16];
  float mx = -1e30f;
#pragma unroll
  for (int e = 0; e < 16; ++e) {
    lg[e] = logits[b * NEXP + e];
    mx = fmaxf(mx, lg[e]);
  }
  float sum = 0.f;
#pragma unroll
  for (int e = 0; e < 16; ++e) {
    lg[e] = __expf(lg[e] - mx);
    sum += lg[e];
  }
  float inv = 1.f / sum;
  float o[8];
#pragma unroll
  for (int j = 0; j < 8; ++j) o[j] = 0.f;
#pragma unroll
  for (int e = 0; e < 16; ++e) {
    float wl = lg[e] * inv;
    const float* p = &eo2[(((size_t)c * NEXP + e) * 8 + b) * H2 + d0];
    float4 x0 = *(const float4*)p;
    float4 x1 = *(const float4*)(p + 4);
    float4 y0 = *(const float4*)(p + 2097152);
    float4 y1 = *(const float4*)(p + 2097152 + 4);
    float4 v0 = *(const float4*)&b2[e * H2 + d0];
    float4 v1 = *(const float4*)&b2[e * H2 + d0 + 4];
    o[0] += wl * (x0.x + y0.x + v0.x);
    o[1] += wl * (x0.y + y0.y + v0.y);
    o[2] += wl * (x0.z + y0.z + v0.z);
    o[3] += wl * (x0.w + y0.w + v0.w);
    o[4] += wl * (x1.x + y1.x + v1.x);
    o[5] += wl * (x1.y + y1.y + v1.y);
    o[6] += wl * (x1.z + y1.z + v1.z);
    o[7] += wl * (x1.w + y1.w + v1.w);
  }
  union { short8 v; unsigned u[4]; } p;
#pragma unroll
  for (int q = 0; q < 4; ++q) p.u[q] = pk_bf16(o[2 * q], o[2 * q + 1]);
  int kb = dc >> 3;
  int cpx = (dc & 7) ^ (b & 7);
  *(short8*)&z_t[((size_t)kb * 256 + m) * 64 + cpx * 8] = p.v;
}

// ---- K5: out = z @ [WA|WB] + bias. BM=256 (no M split: every WA/WB byte
// read ONCE, fp32 direct, no pack). 256 blocks = nt; BN=128 BK=64 K=512.
// 512 thr, 8 waves (4m x 2n), wave tile 64x64. B transpose = per-column
// register gather (coalesced across lanes) + in-reg bf16 pack + swizzled write.
__global__ void __launch_bounds__(512) k_lora2(const unsigned short* __restrict__ z_t,
                                               const float* __restrict__ WA,
                                               const float* __restrict__ WB,
                                               const float* __restrict__ bA,
                                               const float* __restrict__ bB,
                                               float* __restrict__ out) {
  __shared__ __align__(16) unsigned short As[16384];   // 256 x 64 (32KB)
  __shared__ __align__(16) unsigned short Bs[8192];    // 128 x 64 (16KB)
  int nt = blockIdx.x;
  int t = threadIdx.x, lane = t & 63, w = t >> 6;
  int wm = w >> 1, wn = w & 1;
  int fr = lane & 15, quad = lane >> 4, key = fr & 7;
  int ms = nt >> 7;
  const float* Wsrc = ms ? WB : WA;
  int col0 = (nt & 127) * 128;
  // B staging: thread -> (column bn 0..127, k-group kg 0..3 of 16 rows)
  int bn = t & 127, kg = t >> 7;
  const float* bw = Wsrc + col0 + bn;
  unsigned short* bd0 = &Bs[bn * 64 + (((kg * 2) ^ (bn & 7)) * 8)];
  unsigned short* bd1 = &Bs[bn * 64 + (((kg * 2 + 1) ^ (bn & 7)) * 8)];

  floatx4 zero4 = {0.f, 0.f, 0.f, 0.f};
  floatx4 acc[4][4];
#pragma unroll
  for (int i = 0; i < 4; ++i)
#pragma unroll
    for (int j = 0; j < 4; ++j) acc[i][j] = zero4;

  for (int kb = 0; kb < 8; ++kb) {
    __syncthreads();
    // A: z_t (256KB total, L2-resident) via async global->LDS
    const unsigned short* asrc = z_t + (size_t)kb * 16384 + t * 8;
    gl16(asrc, &As[t * 8]);
    gl16(asrc + 4096, &As[t * 8 + 4096]);
    gl16(asrc + 8192, &As[t * 8 + 8192]);
    gl16(asrc + 12288, &As[t * 8 + 12288]);
    // B: 16 coalesced row-loads (lanes span columns), pack to bf16, swizzle-write
    const float* bk = bw + (size_t)(kb * 64 + kg * 16) * NBIG;
    float v[16];
#pragma unroll
    for (int kr = 0; kr < 16; ++kr) v[kr] = bk[(size_t)kr * NBIG];
    union { short8 s; unsigned u[4]; } q0, q1;
#pragma unroll
    for (int q = 0; q < 4; ++q) {
      q0.u[q] = pk_bf16(v[2 * q], v[2 * q + 1]);
      q1.u[q] = pk_bf16(v[8 + 2 * q], v[9 + 2 * q]);
    }
    *(short8*)bd0 = q0.s;
    *(short8*)bd1 = q1.s;
    __syncthreads();
#pragma unroll
    for (int ks2 = 0; ks2 < 2; ++ks2) {
      int cof = ((ks2 * 4 + quad) ^ key) * 8;
      short8 bf0 = *(const short8*)&Bs[(wn * 64 + fr) * 64 + cof];
      short8 bf1 = *(const short8*)&Bs[(wn * 64 + 16 + fr) * 64 + cof];
      short8 bf2 = *(const short8*)&Bs[(wn * 64 + 32 + fr) * 64 + cof];
      short8 bf3 = *(const short8*)&Bs[(wn * 64 + 48 + fr) * 64 + cof];
#pragma unroll
      for (int rt = 0; rt < 4; ++rt) {
        short8 af = *(const short8*)&As[(wm * 64 + rt * 16 + fr) * 64 + cof];
        acc[rt][0] = __builtin_amdgcn_mfma_f32_16x16x32_bf16(af, bf0, acc[rt][0], 0, 0, 0);
        acc[rt][1] = __builtin_amdgcn_mfma_f32_16x16x32_bf16(af, bf1, acc[rt][1], 0, 0, 0);
        acc[rt][2] = __builtin_amdgcn_mfma_f32_16x16x32_bf16(af, bf2, acc[rt][2], 0, 0, 0);
        acc[rt][3] = __builtin_amdgcn_mfma_f32_16x16x32_bf16(af, bf3, acc[rt][3], 0, 0, 0);
      }
    }
  }
  const float* bias = ms ? bB : bA;
  float* obase = out + (size_t)ms * 4194304;
#pragma unroll
  for (int nj = 0; nj < 4; ++nj) {
    int nn = col0 + wn * 64 + nj * 16 + fr;
    float bv = bias[nn];
#pragma unroll
    for (int rt = 0; rt < 4; ++rt) {
#pragma unroll
      for (int i2 = 0; i2 < 4; ++i2) {
        int m = wm * 64 + rt * 16 + quad * 4 + i2;
        obase[(size_t)m * NBIG + nn] = acc[rt][nj][i2] + bv;
      }
    }
  }
}

extern "C" void kernel_launch(void* const* d_in, const int* in_sizes, int n_in,
                              void* d_out, int out_size, void* d_ws, size_t ws_size,
                              hipStream_t stream) {
  const float* s = (const float*)d_in[0];
  const float* Wg1 = (const float*)d_in[1];
  const float* bg1 = (const float*)d_in[2];
  const float* Wg2 = (const float*)d_in[3];
  const float* bg2 = (const float*)d_in[4];
  const float* W1 = (const float*)d_in[5];
  const float* b1 = (const float*)d_in[6];
  const float* W2 = (const float*)d_in[7];
  const float* b2 = (const float*)d_in[8];
  const float* WA = (const float*)d_in[9];
  const float* bA = (const float*)d_in[10];
  const float* WB = (const float*)d_in[11];
  const float* bB = (const float*)d_in[12];
  float* out = (float*)d_out;

  char* ws = (char*)d_ws;
  float* g1 = (float*)(ws);                                 // 64 KB
  float* logits = (float*)(ws + 65536);                     // 512 B
  float* base = (float*)(ws + 131072);                      // 1 MB -> ends 1179648
  float* eo2 = (float*)(ws + 1179648);                      // 16.78 MB -> 17956864
  unsigned short* z_t = (unsigned short*)(ws + 17956864);   // 256 KB -> 18219008
  unsigned short* W2t = (unsigned short*)(ws + 18219008);   // 33.55 MB -> 51773440

  k_gate1<<<128, 256, 0, stream>>>(s, Wg1, bg1, g1);
  k_gate2<<<16, 256, 0, stream>>>(g1, Wg2, bg2, logits);
  k_base<<<dim3(16, 16), 512, 0, stream>>>(s, W1, b1, base);
  k_packW<<<dim3(8, 32, 16), 256, 0, stream>>>(W2, W2t, H2, H2, 0,
                                               (long)H1 * H2, (long)H1 * H2);
  k_egemm2<<<256, 512, 0, stream>>>(base, W1, W2t, eo2);
  k_mix<<<dim3(32, 2), 256, 0, stream>>>(eo2, logits, b2, z_t);
  k_lora2<<<256, 512, 0, stream>>>(z_t, WA, WB, bA, bB, out);
}

// Round 2
// 376.739 us; speedup vs baseline: 1.0517x; 1.0352x over previous
//
#include <hip/hip_runtime.h>
#include <hip/hip_bf16.h>

#define EMB 1024
#define CTX 32
#define NEXP 16
#define H1 2048
#define H2 512
#define NBIG 16384  // F_IN*R == R*F_OUT

typedef __attribute__((ext_vector_type(8))) short short8;
typedef __attribute__((ext_vector_type(4))) float floatx4;
typedef __attribute__((ext_vector_type(2))) unsigned uint2v;
typedef const __attribute__((address_space(1))) void* gas_t;
typedef __attribute__((address_space(3))) void* las_t;

__device__ __forceinline__ void gl16(const unsigned short* g, unsigned short* l) {
  __builtin_amdgcn_global_load_lds((gas_t)(const void*)g, (las_t)(void*)l, 16, 0, 0);
}

__device__ inline unsigned short bf_bits(float x) {
  unsigned u = __builtin_bit_cast(unsigned, x);
  u += 0x7fffu + ((u >> 16) & 1u);  // round-to-nearest-even
  return (unsigned short)(u >> 16);
}
__device__ inline unsigned pk_bf16(float a, float b) {
  return (unsigned)bf_bits(a) | ((unsigned)bf_bits(b) << 16);
}

// ======== Fused stage A: {k_base | k_packW(W2) | k_gate1} — all independent ====
// grid 4480 x 512thr:
//   [0,256)      base[e,b,h] = s @ W1s + b1          (138 MB read)
//   [256,4352)   W2t pack fp32->tiled bf16            (64 MB read + 32 MB write)
//   [4352,4480)  g1 = relu(s @ Wg1 + bg1)             (8 MB read)
// One smem union (67584 B) -> 2 blocks/CU for every branch.
__global__ void __launch_bounds__(512) k_fusedA(const float* __restrict__ s,
                                                const float* __restrict__ Wg1,
                                                const float* __restrict__ bg1,
                                                const float* __restrict__ W1,
                                                const float* __restrict__ b1,
                                                const float* __restrict__ W2,
                                                float* __restrict__ g1,
                                                float* __restrict__ base,
                                                unsigned short* __restrict__ W2t) {
  __shared__ __align__(16) char smem[67584];
  int bid = blockIdx.x;
  int t = threadIdx.x;

  if (bid < 256) {
    // ---------------- base: e = bid>>4, ht = bid&15 ----------------
    float* sl = (float*)smem;                                  // 8*EMB floats (32KB)
    float(*red)[64][17] = (float(*)[64][17])(smem + 32768);    // [8][64][17] (34816B)
    int ht = bid & 15;
    int e = bid >> 4;
#pragma unroll
    for (int i = 0; i < 4; ++i) {
      int idx = (t + i * 512) * 4;
      *(float4*)&sl[idx] = *(const float4*)&s[idx];
    }
    __syncthreads();
    int hp = t & 63;
    int kk = t >> 6;
    int h = ht * 128 + hp * 2;
    const float* wp = W1 + (size_t)e * 1056 * H1 + h;
    float a0[8], a1[8];
#pragma unroll
    for (int b = 0; b < 8; ++b) { a0[b] = 0.f; a1[b] = 0.f; }
    int k0 = kk * 128;
    for (int k = k0; k < k0 + 128; ++k) {
      float2 w = *(const float2*)(wp + (size_t)k * H1);
#pragma unroll
      for (int b = 0; b < 8; ++b) {
        float sv = sl[b * EMB + k];
        a0[b] += sv * w.x;
        a1[b] += sv * w.y;
      }
    }
#pragma unroll
    for (int b = 0; b < 8; ++b) {
      red[kk][hp][b * 2] = a0[b];
      red[kk][hp][b * 2 + 1] = a1[b];
    }
    __syncthreads();
    if (t < 64) {
      int hh = ht * 128 + t * 2;
#pragma unroll
      for (int b = 0; b < 8; ++b) {
        float v0 = 0.f, v1 = 0.f;
#pragma unroll
        for (int q = 0; q < 8; ++q) {
          v0 += red[q][t][b * 2];
          v1 += red[q][t][b * 2 + 1];
        }
        float2 bv = *(const float2*)&b1[e * H1 + hh];
        float2 o;
        o.x = v0 + bv.x;
        o.y = v1 + bv.y;
        *(float2*)&base[(size_t)(e * 8 + b) * H1 + hh] = o;
      }
    }
  } else if (bid < 4352) {
    // ---------------- packW(W2): pid = nt + 8*kb + 256*e ----------------
    float(*tl)[65] = (float(*)[65])smem;                       // [64][65] (16640B)
    int pid = bid - 256;
    int nt = pid & 7, kb = (pid >> 3) & 31, e = pid >> 8;
    const float* S = W2 + (size_t)e * H1 * H2 + (size_t)kb * 64 * H2 + nt * 64;
    int r = t >> 4, c4 = (t & 15) * 4;
#pragma unroll
    for (int i = 0; i < 2; ++i) {
      int row = r + i * 32;
      float4 v = *(const float4*)&S[(size_t)row * H2 + c4];
      *(float4*)&tl[row][c4] = v;
    }
    __syncthreads();
    int nl = t >> 3;
    int cp = t & 7;
    int key = nl & 7;
    unsigned short* D = W2t + (size_t)e * 1048576 +
                        ((size_t)kb * 512 + nt * 64 + nl) * 64;
    int k0 = (cp ^ key) * 8;
    union { short8 v; unsigned u[4]; } p;
#pragma unroll
    for (int q = 0; q < 4; ++q)
      p.u[q] = pk_bf16(tl[k0 + 2 * q][nl], tl[k0 + 2 * q + 1][nl]);
    *(short8*)&D[cp * 8] = p.v;
  } else {
    // ---------------- gate1: gid = bid-4352, 512thr (32 k-chunks) ----------------
    float(*red1)[16][8] = (float(*)[16][8])smem;               // [32][16][8] (16384B)
    int gid = bid - 4352;
    int c = t & 15, kk = t >> 4;
    int h = gid * 16 + c;
    float acc[8];
#pragma unroll
    for (int b = 0; b < 8; ++b) acc[b] = 0.f;
    int k0 = kk * 32;
    for (int k = k0; k < k0 + 32; ++k) {
      float w = Wg1[(size_t)k * H1 + h];
#pragma unroll
      for (int b = 0; b < 8; ++b) acc[b] += s[b * EMB + k] * w;
    }
#pragma unroll
    for (int b = 0; b < 8; ++b) red1[kk][c][b] = acc[b];
    __syncthreads();
    if (t < 128) {
      int cc = t >> 3, b = t & 7;
      float v = 0.f;
#pragma unroll
      for (int q = 0; q < 32; ++q) v += red1[q][cc][b];
      int hh = gid * 16 + cc;
      v += bg1[hh];
      g1[b * H1 + hh] = fmaxf(v, 0.f);
    }
  }
}

// ======== Fused stage B: {k_egemm2 | k_gate2} ====
// grid 272 x 512thr: [0,256) egemm (needs base,W2t), [256,272) gate2 (needs g1).
__global__ void __launch_bounds__(512) k_fusedB(const float* __restrict__ base,
                                                const float* __restrict__ W1,
                                                const unsigned short* __restrict__ W2t,
                                                const float* __restrict__ g1,
                                                const float* __restrict__ Wg2,
                                                const float* __restrict__ bg2,
                                                float* __restrict__ eo2,
                                                float* __restrict__ logits) {
  __shared__ __align__(16) char smemB[40960];
  int bid = blockIdx.x;
  int t = threadIdx.x;

  if (bid < 256) {
    // ---- egemm: eo2[ks][c,e,b,d] = relu(base+W1c) @ W2 (fused-h A staging) ----
    unsigned short* As = (unsigned short*)smemB;           // 64 x 64 (8KB)
    unsigned short* Bs = (unsigned short*)(smemB + 8192);  // 256 x 64 (32KB)
    int id = bid;
    int mt = id >> 6, rem = id & 63;
    int e = rem >> 2, nt = (rem >> 1) & 1, ks = rem & 1;
    int lane = t & 63, w = t >> 6;
    int wm = w >> 2, wn = w & 3;  // 2 x 4 wave grid, wave tile 32m x 64n
    int fr = lane & 15, quad = lane >> 4, key = fr & 7;

    int am = t >> 3;
    int ak = (t & 7) * 8;
    const float* bp = base + ((size_t)e * 8 + (am & 7)) * H1;
    const float* cp = W1 + ((size_t)e * 1056 + EMB + mt * 8 + (am >> 3)) * H1;
    unsigned short* adst = &As[am * 64 + (((t & 7) ^ (am & 7)) * 8)];
    const unsigned short* wBe = W2t + (size_t)e * 1048576 + (size_t)nt * 16384;

    floatx4 zero4 = {0.f, 0.f, 0.f, 0.f};
    floatx4 acc[2][4];
#pragma unroll
    for (int i = 0; i < 2; ++i)
#pragma unroll
      for (int j = 0; j < 4; ++j) acc[i][j] = zero4;

    for (int i = 0; i < 16; ++i) {
      int kb = ks * 16 + i;
      __syncthreads();
      const unsigned short* bsrc = wBe + (size_t)kb * 32768 + t * 8;
      gl16(bsrc, &Bs[t * 8]);
      gl16(bsrc + 4096, &Bs[t * 8 + 4096]);
      gl16(bsrc + 8192, &Bs[t * 8 + 8192]);
      gl16(bsrc + 12288, &Bs[t * 8 + 12288]);
      int k0 = kb * 64 + ak;
      float4 x0 = *(const float4*)&bp[k0];
      float4 x1 = *(const float4*)&bp[k0 + 4];
      float4 y0 = *(const float4*)&cp[k0];
      float4 y1 = *(const float4*)&cp[k0 + 4];
      union { short8 v; unsigned u[4]; } pq;
      pq.u[0] = pk_bf16(fmaxf(x0.x + y0.x, 0.f), fmaxf(x0.y + y0.y, 0.f));
      pq.u[1] = pk_bf16(fmaxf(x0.z + y0.z, 0.f), fmaxf(x0.w + y0.w, 0.f));
      pq.u[2] = pk_bf16(fmaxf(x1.x + y1.x, 0.f), fmaxf(x1.y + y1.y, 0.f));
      pq.u[3] = pk_bf16(fmaxf(x1.z + y1.z, 0.f), fmaxf(x1.w + y1.w, 0.f));
      *(short8*)adst = pq.v;
      __syncthreads();
#pragma unroll
      for (int ks2 = 0; ks2 < 2; ++ks2) {
        int cof = ((ks2 * 4 + quad) ^ key) * 8;
        short8 a0 = *(const short8*)&As[(wm * 32 + fr) * 64 + cof];
        short8 a1 = *(const short8*)&As[(wm * 32 + 16 + fr) * 64 + cof];
#pragma unroll
        for (int nj = 0; nj < 4; ++nj) {
          short8 bf = *(const short8*)&Bs[(wn * 64 + nj * 16 + fr) * 64 + cof];
          acc[0][nj] = __builtin_amdgcn_mfma_f32_16x16x32_bf16(a0, bf, acc[0][nj], 0, 0, 0);
          acc[1][nj] = __builtin_amdgcn_mfma_f32_16x16x32_bf16(a1, bf, acc[1][nj], 0, 0, 0);
        }
      }
    }
    float* op = eo2 + (size_t)ks * 2097152;
    int d0 = nt * 256 + wn * 64 + fr;
#pragma unroll
    for (int nj = 0; nj < 4; ++nj) {
      int d = d0 + nj * 16;
#pragma unroll
      for (int rt = 0; rt < 2; ++rt) {
#pragma unroll
        for (int i2 = 0; i2 < 4; ++i2) {
          int gm = mt * 64 + wm * 32 + rt * 16 + quad * 4 + i2;
          op[(((size_t)(gm >> 3) * NEXP + e) * 8 + (gm & 7)) * H2 + d] = acc[rt][nj][i2];
        }
      }
    }
  } else {
    // ---------------- gate2: e = bid-256, 512thr (4 k each) ----------------
    float(*red)[8] = (float(*)[8])smemB;  // [512][8] (16KB)
    int e = bid - 256;
    int k0 = t * 4;
    float wv[4];
#pragma unroll
    for (int j = 0; j < 4; ++j) wv[j] = Wg2[(size_t)(k0 + j) * NEXP + e];
    float acc[8];
#pragma unroll
    for (int b = 0; b < 8; ++b) {
      float4 ga = *(const float4*)&g1[b * H1 + k0];
      acc[b] = ga.x * wv[0] + ga.y * wv[1] + ga.z * wv[2] + ga.w * wv[3];
    }
#pragma unroll
    for (int b = 0; b < 8; ++b) red[t][b] = acc[b];
    __syncthreads();
    for (int off = 256; off > 0; off >>= 1) {
      if (t < off) {
#pragma unroll
        for (int b = 0; b < 8; ++b) red[t][b] += red[t + off][b];
      }
      __syncthreads();
    }
    if (t < 8) logits[t * NEXP + e] = red[0][t] + bg2[e];
  }
}

// ---- K4: z_t tiled bf16 = sum_e softmax * (eo2a+eo2b+b2). grid (32,4) ----
__global__ void __launch_bounds__(256) k_mix(const float* __restrict__ eo2,
                                             const float* __restrict__ logits,
                                             const float* __restrict__ b2,
                                             unsigned short* __restrict__ z_t) {
  int c = blockIdx.x, by = blockIdx.y, t = threadIdx.x;
  int b = t >> 5;
  int x = t & 31;
  int dc = by * 16 + (x >> 1);   // 8-float chunk index (0..63)
  int part = x & 1;              // which 4-float half of the chunk
  int d0 = dc * 8 + part * 4;
  int m = c * 8 + b;
  float lg[16];
  float mx = -1e30f;
#pragma unroll
  for (int e = 0; e < 16; ++e) {
    lg[e] = logits[b * NEXP + e];
    mx = fmaxf(mx, lg[e]);
  }
  float sum = 0.f;
#pragma unroll
  for (int e = 0; e < 16; ++e) {
    lg[e] = __expf(lg[e] - mx);
    sum += lg[e];
  }
  float inv = 1.f / sum;
  float o[4];
#pragma unroll
  for (int j = 0; j < 4; ++j) o[j] = 0.f;
#pragma unroll
  for (int e = 0; e < 16; ++e) {
    float wl = lg[e] * inv;
    const float* p = &eo2[(((size_t)c * NEXP + e) * 8 + b) * H2 + d0];
    float4 x0 = *(const float4*)p;
    float4 y0 = *(const float4*)(p + 2097152);
    float4 v0 = *(const float4*)&b2[e * H2 + d0];
    o[0] += wl * (x0.x + y0.x + v0.x);
    o[1] += wl * (x0.y + y0.y + v0.y);
    o[2] += wl * (x0.z + y0.z + v0.z);
    o[3] += wl * (x0.w + y0.w + v0.w);
  }
  uint2v p;
  p.x = pk_bf16(o[0], o[1]);
  p.y = pk_bf16(o[2], o[3]);
  int kb = dc >> 3;
  int cpx = (dc & 7) ^ (b & 7);
  *(uint2v*)&z_t[((size_t)kb * 256 + m) * 64 + cpx * 8 + part * 4] = p;
}

// ---- K5: out = z @ [WA|WB] + bias. BM=256 (every WA/WB byte read ONCE). ----
__global__ void __launch_bounds__(512) k_lora2(const unsigned short* __restrict__ z_t,
                                               const float* __restrict__ WA,
                                               const float* __restrict__ WB,
                                               const float* __restrict__ bA,
                                               const float* __restrict__ bB,
                                               float* __restrict__ out) {
  __shared__ __align__(16) unsigned short As[16384];   // 256 x 64 (32KB)
  __shared__ __align__(16) unsigned short Bs[8192];    // 128 x 64 (16KB)
  int nt = blockIdx.x;
  int t = threadIdx.x, lane = t & 63, w = t >> 6;
  int wm = w >> 1, wn = w & 1;
  int fr = lane & 15, quad = lane >> 4, key = fr & 7;
  int ms = nt >> 7;
  const float* Wsrc = ms ? WB : WA;
  int col0 = (nt & 127) * 128;
  int bn = t & 127, kg = t >> 7;
  const float* bw = Wsrc + col0 + bn;
  unsigned short* bd0 = &Bs[bn * 64 + (((kg * 2) ^ (bn & 7)) * 8)];
  unsigned short* bd1 = &Bs[bn * 64 + (((kg * 2 + 1) ^ (bn & 7)) * 8)];

  floatx4 zero4 = {0.f, 0.f, 0.f, 0.f};
  floatx4 acc[4][4];
#pragma unroll
  for (int i = 0; i < 4; ++i)
#pragma unroll
    for (int j = 0; j < 4; ++j) acc[i][j] = zero4;

  for (int kb = 0; kb < 8; ++kb) {
    __syncthreads();
    const unsigned short* asrc = z_t + (size_t)kb * 16384 + t * 8;
    gl16(asrc, &As[t * 8]);
    gl16(asrc + 4096, &As[t * 8 + 4096]);
    gl16(asrc + 8192, &As[t * 8 + 8192]);
    gl16(asrc + 12288, &As[t * 8 + 12288]);
    const float* bk = bw + (size_t)(kb * 64 + kg * 16) * NBIG;
    float v[16];
#pragma unroll
    for (int kr = 0; kr < 16; ++kr) v[kr] = bk[(size_t)kr * NBIG];
    union { short8 s; unsigned u[4]; } q0, q1;
#pragma unroll
    for (int q = 0; q < 4; ++q) {
      q0.u[q] = pk_bf16(v[2 * q], v[2 * q + 1]);
      q1.u[q] = pk_bf16(v[8 + 2 * q], v[9 + 2 * q]);
    }
    *(short8*)bd0 = q0.s;
    *(short8*)bd1 = q1.s;
    __syncthreads();
#pragma unroll
    for (int ks2 = 0; ks2 < 2; ++ks2) {
      int cof = ((ks2 * 4 + quad) ^ key) * 8;
      short8 bf0 = *(const short8*)&Bs[(wn * 64 + fr) * 64 + cof];
      short8 bf1 = *(const short8*)&Bs[(wn * 64 + 16 + fr) * 64 + cof];
      short8 bf2 = *(const short8*)&Bs[(wn * 64 + 32 + fr) * 64 + cof];
      short8 bf3 = *(const short8*)&Bs[(wn * 64 + 48 + fr) * 64 + cof];
#pragma unroll
      for (int rt = 0; rt < 4; ++rt) {
        short8 af = *(const short8*)&As[(wm * 64 + rt * 16 + fr) * 64 + cof];
        acc[rt][0] = __builtin_amdgcn_mfma_f32_16x16x32_bf16(af, bf0, acc[rt][0], 0, 0, 0);
        acc[rt][1] = __builtin_amdgcn_mfma_f32_16x16x32_bf16(af, bf1, acc[rt][1], 0, 0, 0);
        acc[rt][2] = __builtin_amdgcn_mfma_f32_16x16x32_bf16(af, bf2, acc[rt][2], 0, 0, 0);
        acc[rt][3] = __builtin_amdgcn_mfma_f32_16x16x32_bf16(af, bf3, acc[rt][3], 0, 0, 0);
      }
    }
  }
  const float* bias = ms ? bB : bA;
  float* obase = out + (size_t)ms * 4194304;
#pragma unroll
  for (int nj = 0; nj < 4; ++nj) {
    int nn = col0 + wn * 64 + nj * 16 + fr;
    float bv = bias[nn];
#pragma unroll
    for (int rt = 0; rt < 4; ++rt) {
#pragma unroll
      for (int i2 = 0; i2 < 4; ++i2) {
        int m = wm * 64 + rt * 16 + quad * 4 + i2;
        obase[(size_t)m * NBIG + nn] = acc[rt][nj][i2] + bv;
      }
    }
  }
}

extern "C" void kernel_launch(void* const* d_in, const int* in_sizes, int n_in,
                              void* d_out, int out_size, void* d_ws, size_t ws_size,
                              hipStream_t stream) {
  const float* s = (const float*)d_in[0];
  const float* Wg1 = (const float*)d_in[1];
  const float* bg1 = (const float*)d_in[2];
  const float* Wg2 = (const float*)d_in[3];
  const float* bg2 = (const float*)d_in[4];
  const float* W1 = (const float*)d_in[5];
  const float* b1 = (const float*)d_in[6];
  const float* W2 = (const float*)d_in[7];
  const float* b2 = (const float*)d_in[8];
  const float* WA = (const float*)d_in[9];
  const float* bA = (const float*)d_in[10];
  const float* WB = (const float*)d_in[11];
  const float* bB = (const float*)d_in[12];
  float* out = (float*)d_out;

  char* ws = (char*)d_ws;
  float* g1 = (float*)(ws);                                 // 64 KB
  float* logits = (float*)(ws + 65536);                     // 512 B
  float* base = (float*)(ws + 131072);                      // 1 MB -> ends 1179648
  float* eo2 = (float*)(ws + 1179648);                      // 16.78 MB -> 17956864
  unsigned short* z_t = (unsigned short*)(ws + 17956864);   // 256 KB -> 18219008
  unsigned short* W2t = (unsigned short*)(ws + 18219008);   // 33.55 MB -> 51773440

  k_fusedA<<<4480, 512, 0, stream>>>(s, Wg1, bg1, W1, b1, W2, g1, base, W2t);
  k_fusedB<<<272, 512, 0, stream>>>(base, W1, W2t, g1, Wg2, bg2, eo2, logits);
  k_mix<<<dim3(32, 4), 256, 0, stream>>>(eo2, logits, b2, z_t);
  k_lora2<<<256, 512, 0, stream>>>(z_t, WA, WB, bA, bB, out);
}

// Round 3
// 371.325 us; speedup vs baseline: 1.0670x; 1.0146x over previous
//
#include <hip/hip_runtime.h>
#include <hip/hip_bf16.h>

#define EMB 1024
#define CTX 32
#define NEXP 16
#define H1 2048
#define H2 512
#define NBIG 16384  // F_IN*R == R*F_OUT

typedef __attribute__((ext_vector_type(8))) short short8;
typedef __attribute__((ext_vector_type(4))) float floatx4;
typedef __attribute__((ext_vector_type(2))) unsigned uint2v;
typedef const __attribute__((address_space(1))) void* gas_t;
typedef __attribute__((address_space(3))) void* las_t;

__device__ __forceinline__ void gl16(const unsigned short* g, unsigned short* l) {
  __builtin_amdgcn_global_load_lds((gas_t)(const void*)g, (las_t)(void*)l, 16, 0, 0);
}

__device__ inline unsigned short bf_bits(float x) {
  unsigned u = __builtin_bit_cast(unsigned, x);
  u += 0x7fffu + ((u >> 16) & 1u);  // round-to-nearest-even
  return (unsigned short)(u >> 16);
}
__device__ inline unsigned pk_bf16(float a, float b) {
  return (unsigned)bf_bits(a) | ((unsigned)bf_bits(b) << 16);
}

// ======== Fused stage A: {k_base | k_packW(W2) | k_gate1} — all independent ====
// grid 4480 x 512thr. LDS cut to 34816B (base aliases sl/red with a barrier)
// -> 4 blocks/CU, 32 waves/CU (max occupancy) for latency hiding.
__global__ void __launch_bounds__(512) k_fusedA(const float* __restrict__ s,
                                                const float* __restrict__ Wg1,
                                                const float* __restrict__ bg1,
                                                const float* __restrict__ W1,
                                                const float* __restrict__ b1,
                                                const float* __restrict__ W2,
                                                float* __restrict__ g1,
                                                float* __restrict__ base,
                                                unsigned short* __restrict__ W2t) {
  __shared__ __align__(16) char smem[34816];
  int bid = blockIdx.x;
  int t = threadIdx.x;

  if (bid < 256) {
    // ---------------- base: e = bid>>4, ht = bid&15 ----------------
    // phase 1: sl = s staged (32KB); phase 2 (after barrier): red aliases smem.
    float* sl = (float*)smem;  // 8*EMB floats
    int ht = bid & 15;
    int e = bid >> 4;
#pragma unroll
    for (int i = 0; i < 4; ++i) {
      int idx = (t + i * 512) * 4;
      *(float4*)&sl[idx] = *(const float4*)&s[idx];
    }
    __syncthreads();
    int hp = t & 63;
    int kk = t >> 6;
    int h = ht * 128 + hp * 2;
    const float* wp = W1 + (size_t)e * 1056 * H1 + h;
    float a0[8], a1[8];
#pragma unroll
    for (int b = 0; b < 8; ++b) { a0[b] = 0.f; a1[b] = 0.f; }
    int k0 = kk * 128;
#pragma unroll 4
    for (int k = k0; k < k0 + 128; ++k) {
      float2 w = *(const float2*)(wp + (size_t)k * H1);
#pragma unroll
      for (int b = 0; b < 8; ++b) {
        float sv = sl[b * EMB + k];
        a0[b] += sv * w.x;
        a1[b] += sv * w.y;
      }
    }
    __syncthreads();  // all waves done reading sl; smem reused as red
    float(*red)[64][17] = (float(*)[64][17])smem;  // [8][64][17] (34816B)
#pragma unroll
    for (int b = 0; b < 8; ++b) {
      red[kk][hp][b * 2] = a0[b];
      red[kk][hp][b * 2 + 1] = a1[b];
    }
    __syncthreads();
    if (t < 64) {
      int hh = ht * 128 + t * 2;
#pragma unroll
      for (int b = 0; b < 8; ++b) {
        float v0 = 0.f, v1 = 0.f;
#pragma unroll
        for (int q = 0; q < 8; ++q) {
          v0 += red[q][t][b * 2];
          v1 += red[q][t][b * 2 + 1];
        }
        float2 bv = *(const float2*)&b1[e * H1 + hh];
        float2 o;
        o.x = v0 + bv.x;
        o.y = v1 + bv.y;
        *(float2*)&base[(size_t)(e * 8 + b) * H1 + hh] = o;
      }
    }
  } else if (bid < 4352) {
    // ---------------- packW(W2): pid = nt + 8*kb + 256*e ----------------
    float(*tl)[65] = (float(*)[65])smem;  // [64][65] (16640B)
    int pid = bid - 256;
    int nt = pid & 7, kb = (pid >> 3) & 31, e = pid >> 8;
    const float* S = W2 + (size_t)e * H1 * H2 + (size_t)kb * 64 * H2 + nt * 64;
    int r = t >> 4, c4 = (t & 15) * 4;
#pragma unroll
    for (int i = 0; i < 2; ++i) {
      int row = r + i * 32;
      float4 v = *(const float4*)&S[(size_t)row * H2 + c4];
      *(float4*)&tl[row][c4] = v;
    }
    __syncthreads();
    int nl = t >> 3;
    int cp = t & 7;
    int key = nl & 7;
    unsigned short* D = W2t + (size_t)e * 1048576 +
                        ((size_t)kb * 512 + nt * 64 + nl) * 64;
    int k0 = (cp ^ key) * 8;
    union { short8 v; unsigned u[4]; } p;
#pragma unroll
    for (int q = 0; q < 4; ++q)
      p.u[q] = pk_bf16(tl[k0 + 2 * q][nl], tl[k0 + 2 * q + 1][nl]);
    *(short8*)&D[cp * 8] = p.v;
  } else {
    // ---------------- gate1: gid = bid-4352, 512thr (32 k-chunks) ----------------
    float(*red1)[16][8] = (float(*)[16][8])smem;  // [32][16][8] (16384B)
    int gid = bid - 4352;
    int c = t & 15, kk = t >> 4;
    int h = gid * 16 + c;
    float acc[8];
#pragma unroll
    for (int b = 0; b < 8; ++b) acc[b] = 0.f;
    int k0 = kk * 32;
    for (int k = k0; k < k0 + 32; ++k) {
      float w = Wg1[(size_t)k * H1 + h];
#pragma unroll
      for (int b = 0; b < 8; ++b) acc[b] += s[b * EMB + k] * w;
    }
#pragma unroll
    for (int b = 0; b < 8; ++b) red1[kk][c][b] = acc[b];
    __syncthreads();
    if (t < 128) {
      int cc = t >> 3, b = t & 7;
      float v = 0.f;
#pragma unroll
      for (int q = 0; q < 32; ++q) v += red1[q][cc][b];
      int hh = gid * 16 + cc;
      v += bg1[hh];
      g1[b * H1 + hh] = fmaxf(v, 0.f);
    }
  }
}

// ======== Fused stage B: {k_egemm2 | k_gate2} ====
// grid 272 x 512thr: [0,256) egemm (needs base,W2t), [256,272) gate2 (needs g1).
__global__ void __launch_bounds__(512) k_fusedB(const float* __restrict__ base,
                                                const float* __restrict__ W1,
                                                const unsigned short* __restrict__ W2t,
                                                const float* __restrict__ g1,
                                                const float* __restrict__ Wg2,
                                                const float* __restrict__ bg2,
                                                float* __restrict__ eo2,
                                                float* __restrict__ logits) {
  __shared__ __align__(16) char smemB[40960];
  int bid = blockIdx.x;
  int t = threadIdx.x;

  if (bid < 256) {
    // ---- egemm: eo2[ks][c,e,b,d] = relu(base+W1c) @ W2 (fused-h A staging) ----
    unsigned short* As = (unsigned short*)smemB;           // 64 x 64 (8KB)
    unsigned short* Bs = (unsigned short*)(smemB + 8192);  // 256 x 64 (32KB)
    int id = bid;
    int mt = id >> 6, rem = id & 63;
    int e = rem >> 2, nt = (rem >> 1) & 1, ks = rem & 1;
    int lane = t & 63, w = t >> 6;
    int wm = w >> 2, wn = w & 3;  // 2 x 4 wave grid, wave tile 32m x 64n
    int fr = lane & 15, quad = lane >> 4, key = fr & 7;

    int am = t >> 3;
    int ak = (t & 7) * 8;
    const float* bp = base + ((size_t)e * 8 + (am & 7)) * H1;
    const float* cp = W1 + ((size_t)e * 1056 + EMB + mt * 8 + (am >> 3)) * H1;
    unsigned short* adst = &As[am * 64 + (((t & 7) ^ (am & 7)) * 8)];
    const unsigned short* wBe = W2t + (size_t)e * 1048576 + (size_t)nt * 16384;

    floatx4 zero4 = {0.f, 0.f, 0.f, 0.f};
    floatx4 acc[2][4];
#pragma unroll
    for (int i = 0; i < 2; ++i)
#pragma unroll
      for (int j = 0; j < 4; ++j) acc[i][j] = zero4;

    for (int i = 0; i < 16; ++i) {
      int kb = ks * 16 + i;
      __syncthreads();
      const unsigned short* bsrc = wBe + (size_t)kb * 32768 + t * 8;
      gl16(bsrc, &Bs[t * 8]);
      gl16(bsrc + 4096, &Bs[t * 8 + 4096]);
      gl16(bsrc + 8192, &Bs[t * 8 + 8192]);
      gl16(bsrc + 12288, &Bs[t * 8 + 12288]);
      int k0 = kb * 64 + ak;
      float4 x0 = *(const float4*)&bp[k0];
      float4 x1 = *(const float4*)&bp[k0 + 4];
      float4 y0 = *(const float4*)&cp[k0];
      float4 y1 = *(const float4*)&cp[k0 + 4];
      union { short8 v; unsigned u[4]; } pq;
      pq.u[0] = pk_bf16(fmaxf(x0.x + y0.x, 0.f), fmaxf(x0.y + y0.y, 0.f));
      pq.u[1] = pk_bf16(fmaxf(x0.z + y0.z, 0.f), fmaxf(x0.w + y0.w, 0.f));
      pq.u[2] = pk_bf16(fmaxf(x1.x + y1.x, 0.f), fmaxf(x1.y + y1.y, 0.f));
      pq.u[3] = pk_bf16(fmaxf(x1.z + y1.z, 0.f), fmaxf(x1.w + y1.w, 0.f));
      *(short8*)adst = pq.v;
      __syncthreads();
#pragma unroll
      for (int ks2 = 0; ks2 < 2; ++ks2) {
        int cof = ((ks2 * 4 + quad) ^ key) * 8;
        short8 a0 = *(const short8*)&As[(wm * 32 + fr) * 64 + cof];
        short8 a1 = *(const short8*)&As[(wm * 32 + 16 + fr) * 64 + cof];
#pragma unroll
        for (int nj = 0; nj < 4; ++nj) {
          short8 bf = *(const short8*)&Bs[(wn * 64 + nj * 16 + fr) * 64 + cof];
          acc[0][nj] = __builtin_amdgcn_mfma_f32_16x16x32_bf16(a0, bf, acc[0][nj], 0, 0, 0);
          acc[1][nj] = __builtin_amdgcn_mfma_f32_16x16x32_bf16(a1, bf, acc[1][nj], 0, 0, 0);
        }
      }
    }
    float* op = eo2 + (size_t)ks * 2097152;
    int d0 = nt * 256 + wn * 64 + fr;
#pragma unroll
    for (int nj = 0; nj < 4; ++nj) {
      int d = d0 + nj * 16;
#pragma unroll
      for (int rt = 0; rt < 2; ++rt) {
#pragma unroll
        for (int i2 = 0; i2 < 4; ++i2) {
          int gm = mt * 64 + wm * 32 + rt * 16 + quad * 4 + i2;
          op[(((size_t)(gm >> 3) * NEXP + e) * 8 + (gm & 7)) * H2 + d] = acc[rt][nj][i2];
        }
      }
    }
  } else {
    // ---------------- gate2: e = bid-256, 512thr (4 k each) ----------------
    float(*red)[8] = (float(*)[8])smemB;  // [512][8] (16KB)
    int e = bid - 256;
    int k0 = t * 4;
    float wv[4];
#pragma unroll
    for (int j = 0; j < 4; ++j) wv[j] = Wg2[(size_t)(k0 + j) * NEXP + e];
    float acc[8];
#pragma unroll
    for (int b = 0; b < 8; ++b) {
      float4 ga = *(const float4*)&g1[b * H1 + k0];
      acc[b] = ga.x * wv[0] + ga.y * wv[1] + ga.z * wv[2] + ga.w * wv[3];
    }
#pragma unroll
    for (int b = 0; b < 8; ++b) red[t][b] = acc[b];
    __syncthreads();
    for (int off = 256; off > 0; off >>= 1) {
      if (t < off) {
#pragma unroll
        for (int b = 0; b < 8; ++b) red[t][b] += red[t + off][b];
      }
      __syncthreads();
    }
    if (t < 8) logits[t * NEXP + e] = red[0][t] + bg2[e];
  }
}

// ---- K4: z_t tiled bf16 = sum_e softmax * (eo2a+eo2b+b2). grid (32,4) ----
__global__ void __launch_bounds__(256) k_mix(const float* __restrict__ eo2,
                                             const float* __restrict__ logits,
                                             const float* __restrict__ b2,
                                             unsigned short* __restrict__ z_t) {
  int c = blockIdx.x, by = blockIdx.y, t = threadIdx.x;
  int b = t >> 5;
  int x = t & 31;
  int dc = by * 16 + (x >> 1);   // 8-float chunk index (0..63)
  int part = x & 1;              // which 4-float half of the chunk
  int d0 = dc * 8 + part * 4;
  int m = c * 8 + b;
  float lg[16];
  float mx = -1e30f;
#pragma unroll
  for (int e = 0; e < 16; ++e) {
    lg[e] = logits[b * NEXP + e];
    mx = fmaxf(mx, lg[e]);
  }
  float sum = 0.f;
#pragma unroll
  for (int e = 0; e < 16; ++e) {
    lg[e] = __expf(lg[e] - mx);
    sum += lg[e];
  }
  float inv = 1.f / sum;
  float o[4];
#pragma unroll
  for (int j = 0; j < 4; ++j) o[j] = 0.f;
#pragma unroll
  for (int e = 0; e < 16; ++e) {
    float wl = lg[e] * inv;
    const float* p = &eo2[(((size_t)c * NEXP + e) * 8 + b) * H2 + d0];
    float4 x0 = *(const float4*)p;
    float4 y0 = *(const float4*)(p + 2097152);
    float4 v0 = *(const float4*)&b2[e * H2 + d0];
    o[0] += wl * (x0.x + y0.x + v0.x);
    o[1] += wl * (x0.y + y0.y + v0.y);
    o[2] += wl * (x0.z + y0.z + v0.z);
    o[3] += wl * (x0.w + y0.w + v0.w);
  }
  uint2v p;
  p.x = pk_bf16(o[0], o[1]);
  p.y = pk_bf16(o[2], o[3]);
  int kb = dc >> 3;
  int cpx = (dc & 7) ^ (b & 7);
  *(uint2v*)&z_t[((size_t)kb * 256 + m) * 64 + cpx * 8 + part * 4] = p;
}

// ---- K5: out = z @ [WA|WB] + bias. BM=256 (every WA/WB byte read ONCE). ----
__global__ void __launch_bounds__(512) k_lora2(const unsigned short* __restrict__ z_t,
                                               const float* __restrict__ WA,
                                               const float* __restrict__ WB,
                                               const float* __restrict__ bA,
                                               const float* __restrict__ bB,
                                               float* __restrict__ out) {
  __shared__ __align__(16) unsigned short As[16384];   // 256 x 64 (32KB)
  __shared__ __align__(16) unsigned short Bs[8192];    // 128 x 64 (16KB)
  int nt = blockIdx.x;
  int t = threadIdx.x, lane = t & 63, w = t >> 6;
  int wm = w >> 1, wn = w & 1;
  int fr = lane & 15, quad = lane >> 4, key = fr & 7;
  int ms = nt >> 7;
  const float* Wsrc = ms ? WB : WA;
  int col0 = (nt & 127) * 128;
  int bn = t & 127, kg = t >> 7;
  const float* bw = Wsrc + col0 + bn;
  unsigned short* bd0 = &Bs[bn * 64 + (((kg * 2) ^ (bn & 7)) * 8)];
  unsigned short* bd1 = &Bs[bn * 64 + (((kg * 2 + 1) ^ (bn & 7)) * 8)];

  floatx4 zero4 = {0.f, 0.f, 0.f, 0.f};
  floatx4 acc[4][4];
#pragma unroll
  for (int i = 0; i < 4; ++i)
#pragma unroll
    for (int j = 0; j < 4; ++j) acc[i][j] = zero4;

  for (int kb = 0; kb < 8; ++kb) {
    __syncthreads();
    const unsigned short* asrc = z_t + (size_t)kb * 16384 + t * 8;
    gl16(asrc, &As[t * 8]);
    gl16(asrc + 4096, &As[t * 8 + 4096]);
    gl16(asrc + 8192, &As[t * 8 + 8192]);
    gl16(asrc + 12288, &As[t * 8 + 12288]);
    const float* bk = bw + (size_t)(kb * 64 + kg * 16) * NBIG;
    float v[16];
#pragma unroll
    for (int kr = 0; kr < 16; ++kr) v[kr] = bk[(size_t)kr * NBIG];
    union { short8 s; unsigned u[4]; } q0, q1;
#pragma unroll
    for (int q = 0; q < 4; ++q) {
      q0.u[q] = pk_bf16(v[2 * q], v[2 * q + 1]);
      q1.u[q] = pk_bf16(v[8 + 2 * q], v[9 + 2 * q]);
    }
    *(short8*)bd0 = q0.s;
    *(short8*)bd1 = q1.s;
    __syncthreads();
#pragma unroll
    for (int ks2 = 0; ks2 < 2; ++ks2) {
      int cof = ((ks2 * 4 + quad) ^ key) * 8;
      short8 bf0 = *(const short8*)&Bs[(wn * 64 + fr) * 64 + cof];
      short8 bf1 = *(const short8*)&Bs[(wn * 64 + 16 + fr) * 64 + cof];
      short8 bf2 = *(const short8*)&Bs[(wn * 64 + 32 + fr) * 64 + cof];
      short8 bf3 = *(const short8*)&Bs[(wn * 64 + 48 + fr) * 64 + cof];
#pragma unroll
      for (int rt = 0; rt < 4; ++rt) {
        short8 af = *(const short8*)&As[(wm * 64 + rt * 16 + fr) * 64 + cof];
        acc[rt][0] = __builtin_amdgcn_mfma_f32_16x16x32_bf16(af, bf0, acc[rt][0], 0, 0, 0);
        acc[rt][1] = __builtin_amdgcn_mfma_f32_16x16x32_bf16(af, bf1, acc[rt][1], 0, 0, 0);
        acc[rt][2] = __builtin_amdgcn_mfma_f32_16x16x32_bf16(af, bf2, acc[rt][2], 0, 0, 0);
        acc[rt][3] = __builtin_amdgcn_mfma_f32_16x16x32_bf16(af, bf3, acc[rt][3], 0, 0, 0);
      }
    }
  }
  const float* bias = ms ? bB : bA;
  float* obase = out + (size_t)ms * 4194304;
#pragma unroll
  for (int nj = 0; nj < 4; ++nj) {
    int nn = col0 + wn * 64 + nj * 16 + fr;
    float bv = bias[nn];
#pragma unroll
    for (int rt = 0; rt < 4; ++rt) {
#pragma unroll
      for (int i2 = 0; i2 < 4; ++i2) {
        int m = wm * 64 + rt * 16 + quad * 4 + i2;
        obase[(size_t)m * NBIG + nn] = acc[rt][nj][i2] + bv;
      }
    }
  }
}

extern "C" void kernel_launch(void* const* d_in, const int* in_sizes, int n_in,
                              void* d_out, int out_size, void* d_ws, size_t ws_size,
                              hipStream_t stream) {
  const float* s = (const float*)d_in[0];
  const float* Wg1 = (const float*)d_in[1];
  const float* bg1 = (const float*)d_in[2];
  const float* Wg2 = (const float*)d_in[3];
  const float* bg2 = (const float*)d_in[4];
  const float* W1 = (const float*)d_in[5];
  const float* b1 = (const float*)d_in[6];
  const float* W2 = (const float*)d_in[7];
  const float* b2 = (const float*)d_in[8];
  const float* WA = (const float*)d_in[9];
  const float* bA = (const float*)d_in[10];
  const float* WB = (const float*)d_in[11];
  const float* bB = (const float*)d_in[12];
  float* out = (float*)d_out;

  char* ws = (char*)d_ws;
  float* g1 = (float*)(ws);                                 // 64 KB
  float* logits = (float*)(ws + 65536);                     // 512 B
  float* base = (float*)(ws + 131072);                      // 1 MB -> ends 1179648
  float* eo2 = (float*)(ws + 1179648);                      // 16.78 MB -> 17956864
  unsigned short* z_t = (unsigned short*)(ws + 17956864);   // 256 KB -> 18219008
  unsigned short* W2t = (unsigned short*)(ws + 18219008);   // 33.55 MB -> 51773440

  k_fusedA<<<4480, 512, 0, stream>>>(s, Wg1, bg1, W1, b1, W2, g1, base, W2t);
  k_fusedB<<<272, 512, 0, stream>>>(base, W1, W2t, g1, Wg2, bg2, eo2, logits);
  k_mix<<<dim3(32, 4), 256, 0, stream>>>(eo2, logits, b2, z_t);
  k_lora2<<<256, 512, 0, stream>>>(z_t, WA, WB, bA, bB, out);
}

// Round 4
// 370.548 us; speedup vs baseline: 1.0693x; 1.0021x over previous
//
#include <hip/hip_runtime.h>
#include <hip/hip_bf16.h>

#define EMB 1024
#define CTX 32
#define NEXP 16
#define H1 2048
#define H2 512
#define NBIG 16384  // F_IN*R == R*F_OUT

typedef __attribute__((ext_vector_type(8))) short short8;
typedef __attribute__((ext_vector_type(4))) float floatx4;
typedef __attribute__((ext_vector_type(2))) unsigned uint2v;
typedef const __attribute__((address_space(1))) void* gas_t;
typedef __attribute__((address_space(3))) void* las_t;

__device__ __forceinline__ void gl16(const unsigned short* g, unsigned short* l) {
  __builtin_amdgcn_global_load_lds((gas_t)(const void*)g, (las_t)(void*)l, 16, 0, 0);
}

__device__ inline unsigned short bf_bits(float x) {
  unsigned u = __builtin_bit_cast(unsigned, x);
  u += 0x7fffu + ((u >> 16) & 1u);  // round-to-nearest-even
  return (unsigned short)(u >> 16);
}
__device__ inline unsigned pk_bf16(float a, float b) {
  return (unsigned)bf_bits(a) | ((unsigned)bf_bits(b) << 16);
}

// ======== Fused stage A: {unified base+gate1 GEMM | k_packW(W2)} ====
// grid 4368 x 256thr:
//   [0,272)     wi = bid>>4 (0..16), tile = bid&15. wi<16: base[e]; wi==16: gate1.
//               M=8, K=1024, N-tile=128. s transposed in LDS (broadcast b128
//               reads), float4 W loads, 32 FMA / iter / thread.
//   [272,4368)  W2t pack fp32->tiled bf16.
// smem 36864B -> 4 blocks/CU.
__global__ void __launch_bounds__(256) k_fusedA(const float* __restrict__ s,
                                                const float* __restrict__ Wg1,
                                                const float* __restrict__ bg1,
                                                const float* __restrict__ W1,
                                                const float* __restrict__ b1,
                                                const float* __restrict__ W2,
                                                float* __restrict__ g1,
                                                float* __restrict__ base,
                                                unsigned short* __restrict__ W2t) {
  __shared__ __align__(16) char smem[36864];
  int bid = blockIdx.x;
  int t = threadIdx.x;

  if (bid < 272) {
    // ---------------- unified base/gate1 ----------------
    int wi = bid >> 4, tile = bid & 15;
    int h0 = tile * 128;
    float* st = (float*)smem;  // st[k][b] : [1024][8] floats (32KB)
    {
      // stage s transposed: thread t -> b = t>>5, k-chunk (t&31)*32
      int b = t >> 5, kc = (t & 31) * 32;
      const float* sp = s + (size_t)b * EMB + kc;
#pragma unroll
      for (int j = 0; j < 32; j += 4) {
        float4 v = *(const float4*)&sp[j];
        st[(kc + j) * 8 + b] = v.x;
        st[(kc + j + 1) * 8 + b] = v.y;
        st[(kc + j + 2) * 8 + b] = v.z;
        st[(kc + j + 3) * 8 + b] = v.w;
      }
    }
    __syncthreads();
    int hp = t & 31, kk = t >> 5;
    const float* wp = (wi < 16 ? W1 + (size_t)wi * 1056 * H1 : Wg1) + h0 + hp * 4;
    floatx4 a[8];
#pragma unroll
    for (int b = 0; b < 8; ++b) a[b] = (floatx4){0.f, 0.f, 0.f, 0.f};
    int k0 = kk * 128;
#pragma unroll 4
    for (int k = k0; k < k0 + 128; ++k) {
      floatx4 w = *(const floatx4*)(wp + (size_t)k * H1);
      float4 s0 = *(const float4*)&st[k * 8];
      float4 s1 = *(const float4*)&st[k * 8 + 4];
      a[0] += s0.x * w;
      a[1] += s0.y * w;
      a[2] += s0.z * w;
      a[3] += s0.w * w;
      a[4] += s1.x * w;
      a[5] += s1.y * w;
      a[6] += s1.z * w;
      a[7] += s1.w * w;
    }
    __syncthreads();  // all waves done reading st; smem reused as red
    float* red = (float*)smem;  // [(kk*32+hp)*36 + b*4 + j] (36864B, 16B-aligned rows)
#pragma unroll
    for (int b = 0; b < 8; ++b)
      *(floatx4*)&red[(kk * 32 + hp) * 36 + b * 4] = a[b];
    __syncthreads();
    {
      int b = t >> 5, hp2 = t & 31;
      floatx4 v = (floatx4){0.f, 0.f, 0.f, 0.f};
#pragma unroll
      for (int q = 0; q < 8; ++q)
        v += *(const floatx4*)&red[(q * 32 + hp2) * 36 + b * 4];
      int h = h0 + hp2 * 4;
      if (wi < 16) {
        floatx4 bv = *(const floatx4*)&b1[wi * H1 + h];
        v += bv;
        *(floatx4*)&base[(size_t)(wi * 8 + b) * H1 + h] = v;
      } else {
        floatx4 bv = *(const floatx4*)&bg1[h];
        v += bv;
        floatx4 z = (floatx4){0.f, 0.f, 0.f, 0.f};
        v = __builtin_elementwise_max(v, z);
        *(floatx4*)&g1[(size_t)b * H1 + h] = v;
      }
    }
  } else {
    // ---------------- packW(W2): pid = nt + 8*kb + 256*e ----------------
    float(*tl)[65] = (float(*)[65])smem;  // [64][65] (16640B)
    int pid = bid - 272;
    int nt = pid & 7, kb = (pid >> 3) & 31, e = pid >> 8;
    const float* S = W2 + (size_t)e * H1 * H2 + (size_t)kb * 64 * H2 + nt * 64;
    int r = t >> 4, c4 = (t & 15) * 4;
#pragma unroll
    for (int i = 0; i < 4; ++i) {
      int row = r + i * 16;
      float4 v = *(const float4*)&S[(size_t)row * H2 + c4];
      *(float4*)&tl[row][c4] = v;
    }
    __syncthreads();
    int nl = t >> 2;
    int cb = (t & 3) * 2;
    int key = nl & 7;
    unsigned short* D = W2t + (size_t)e * 1048576 +
                        ((size_t)kb * 512 + nt * 64 + nl) * 64;
#pragma unroll
    for (int j = 0; j < 2; ++j) {
      int cp = cb + j;
      int k0 = (cp ^ key) * 8;
      union { short8 v; unsigned u[4]; } p;
#pragma unroll
      for (int q = 0; q < 4; ++q)
        p.u[q] = pk_bf16(tl[k0 + 2 * q][nl], tl[k0 + 2 * q + 1][nl]);
      *(short8*)&D[cp * 8] = p.v;
    }
  }
}

// ======== Fused stage B: {k_egemm2 | k_gate2} ====
// grid 272 x 512thr: [0,256) egemm (needs base,W2t), [256,272) gate2 (needs g1).
__global__ void __launch_bounds__(512) k_fusedB(const float* __restrict__ base,
                                                const float* __restrict__ W1,
                                                const unsigned short* __restrict__ W2t,
                                                const float* __restrict__ g1,
                                                const float* __restrict__ Wg2,
                                                const float* __restrict__ bg2,
                                                float* __restrict__ eo2,
                                                float* __restrict__ logits) {
  __shared__ __align__(16) char smemB[40960];
  int bid = blockIdx.x;
  int t = threadIdx.x;

  if (bid < 256) {
    // ---- egemm: eo2[ks][c,e,b,d] = relu(base+W1c) @ W2 (fused-h A staging) ----
    unsigned short* As = (unsigned short*)smemB;           // 64 x 64 (8KB)
    unsigned short* Bs = (unsigned short*)(smemB + 8192);  // 256 x 64 (32KB)
    int id = bid;
    int mt = id >> 6, rem = id & 63;
    int e = rem >> 2, nt = (rem >> 1) & 1, ks = rem & 1;
    int lane = t & 63, w = t >> 6;
    int wm = w >> 2, wn = w & 3;  // 2 x 4 wave grid, wave tile 32m x 64n
    int fr = lane & 15, quad = lane >> 4, key = fr & 7;

    int am = t >> 3;
    int ak = (t & 7) * 8;
    const float* bp = base + ((size_t)e * 8 + (am & 7)) * H1;
    const float* cp = W1 + ((size_t)e * 1056 + EMB + mt * 8 + (am >> 3)) * H1;
    unsigned short* adst = &As[am * 64 + (((t & 7) ^ (am & 7)) * 8)];
    const unsigned short* wBe = W2t + (size_t)e * 1048576 + (size_t)nt * 16384;

    floatx4 zero4 = {0.f, 0.f, 0.f, 0.f};
    floatx4 acc[2][4];
#pragma unroll
    for (int i = 0; i < 2; ++i)
#pragma unroll
      for (int j = 0; j < 4; ++j) acc[i][j] = zero4;

    for (int i = 0; i < 16; ++i) {
      int kb = ks * 16 + i;
      __syncthreads();
      const unsigned short* bsrc = wBe + (size_t)kb * 32768 + t * 8;
      gl16(bsrc, &Bs[t * 8]);
      gl16(bsrc + 4096, &Bs[t * 8 + 4096]);
      gl16(bsrc + 8192, &Bs[t * 8 + 8192]);
      gl16(bsrc + 12288, &Bs[t * 8 + 12288]);
      int k0 = kb * 64 + ak;
      float4 x0 = *(const float4*)&bp[k0];
      float4 x1 = *(const float4*)&bp[k0 + 4];
      float4 y0 = *(const float4*)&cp[k0];
      float4 y1 = *(const float4*)&cp[k0 + 4];
      union { short8 v; unsigned u[4]; } pq;
      pq.u[0] = pk_bf16(fmaxf(x0.x + y0.x, 0.f), fmaxf(x0.y + y0.y, 0.f));
      pq.u[1] = pk_bf16(fmaxf(x0.z + y0.z, 0.f), fmaxf(x0.w + y0.w, 0.f));
      pq.u[2] = pk_bf16(fmaxf(x1.x + y1.x, 0.f), fmaxf(x1.y + y1.y, 0.f));
      pq.u[3] = pk_bf16(fmaxf(x1.z + y1.z, 0.f), fmaxf(x1.w + y1.w, 0.f));
      *(short8*)adst = pq.v;
      __syncthreads();
#pragma unroll
      for (int ks2 = 0; ks2 < 2; ++ks2) {
        int cof = ((ks2 * 4 + quad) ^ key) * 8;
        short8 a0 = *(const short8*)&As[(wm * 32 + fr) * 64 + cof];
        short8 a1 = *(const short8*)&As[(wm * 32 + 16 + fr) * 64 + cof];
#pragma unroll
        for (int nj = 0; nj < 4; ++nj) {
          short8 bf = *(const short8*)&Bs[(wn * 64 + nj * 16 + fr) * 64 + cof];
          acc[0][nj] = __builtin_amdgcn_mfma_f32_16x16x32_bf16(a0, bf, acc[0][nj], 0, 0, 0);
          acc[1][nj] = __builtin_amdgcn_mfma_f32_16x16x32_bf16(a1, bf, acc[1][nj], 0, 0, 0);
        }
      }
    }
    float* op = eo2 + (size_t)ks * 2097152;
    int d0 = nt * 256 + wn * 64 + fr;
#pragma unroll
    for (int nj = 0; nj < 4; ++nj) {
      int d = d0 + nj * 16;
#pragma unroll
      for (int rt = 0; rt < 2; ++rt) {
#pragma unroll
        for (int i2 = 0; i2 < 4; ++i2) {
          int gm = mt * 64 + wm * 32 + rt * 16 + quad * 4 + i2;
          op[(((size_t)(gm >> 3) * NEXP + e) * 8 + (gm & 7)) * H2 + d] = acc[rt][nj][i2];
        }
      }
    }
  } else {
    // ---------------- gate2: e = bid-256, 512thr (4 k each) ----------------
    float(*red)[8] = (float(*)[8])smemB;  // [512][8] (16KB)
    int e = bid - 256;
    int k0 = t * 4;
    float wv[4];
#pragma unroll
    for (int j = 0; j < 4; ++j) wv[j] = Wg2[(size_t)(k0 + j) * NEXP + e];
    float acc[8];
#pragma unroll
    for (int b = 0; b < 8; ++b) {
      float4 ga = *(const float4*)&g1[b * H1 + k0];
      acc[b] = ga.x * wv[0] + ga.y * wv[1] + ga.z * wv[2] + ga.w * wv[3];
    }
#pragma unroll
    for (int b = 0; b < 8; ++b) red[t][b] = acc[b];
    __syncthreads();
    for (int off = 256; off > 0; off >>= 1) {
      if (t < off) {
#pragma unroll
        for (int b = 0; b < 8; ++b) red[t][b] += red[t + off][b];
      }
      __syncthreads();
    }
    if (t < 8) logits[t * NEXP + e] = red[0][t] + bg2[e];
  }
}

// ---- K4: z_t tiled bf16 = sum_e softmax * (eo2a+eo2b+b2). grid (32,4) ----
__global__ void __launch_bounds__(256) k_mix(const float* __restrict__ eo2,
                                             const float* __restrict__ logits,
                                             const float* __restrict__ b2,
                                             unsigned short* __restrict__ z_t) {
  int c = blockIdx.x, by = blockIdx.y, t = threadIdx.x;
  int b = t >> 5;
  int x = t & 31;
  int dc = by * 16 + (x >> 1);   // 8-float chunk index (0..63)
  int part = x & 1;              // which 4-float half of the chunk
  int d0 = dc * 8 + part * 4;
  int m = c * 8 + b;
  float lg[16];
  float mx = -1e30f;
#pragma unroll
  for (int e = 0; e < 16; ++e) {
    lg[e] = logits[b * NEXP + e];
    mx = fmaxf(mx, lg[e]);
  }
  float sum = 0.f;
#pragma unroll
  for (int e = 0; e < 16; ++e) {
    lg[e] = __expf(lg[e] - mx);
    sum += lg[e];
  }
  float inv = 1.f / sum;
  float o[4];
#pragma unroll
  for (int j = 0; j < 4; ++j) o[j] = 0.f;
#pragma unroll
  for (int e = 0; e < 16; ++e) {
    float wl = lg[e] * inv;
    const float* p = &eo2[(((size_t)c * NEXP + e) * 8 + b) * H2 + d0];
    float4 x0 = *(const float4*)p;
    float4 y0 = *(const float4*)(p + 2097152);
    float4 v0 = *(const float4*)&b2[e * H2 + d0];
    o[0] += wl * (x0.x + y0.x + v0.x);
    o[1] += wl * (x0.y + y0.y + v0.y);
    o[2] += wl * (x0.z + y0.z + v0.z);
    o[3] += wl * (x0.w + y0.w + v0.w);
  }
  uint2v p;
  p.x = pk_bf16(o[0], o[1]);
  p.y = pk_bf16(o[2], o[3]);
  int kb = dc >> 3;
  int cpx = (dc & 7) ^ (b & 7);
  *(uint2v*)&z_t[((size_t)kb * 256 + m) * 64 + cpx * 8 + part * 4] = p;
}

// ---- K5: out = z @ [WA|WB] + bias. BM=256 (every WA/WB byte read ONCE). ----
__global__ void __launch_bounds__(512) k_lora2(const unsigned short* __restrict__ z_t,
                                               const float* __restrict__ WA,
                                               const float* __restrict__ WB,
                                               const float* __restrict__ bA,
                                               const float* __restrict__ bB,
                                               float* __restrict__ out) {
  __shared__ __align__(16) unsigned short As[16384];   // 256 x 64 (32KB)
  __shared__ __align__(16) unsigned short Bs[8192];    // 128 x 64 (16KB)
  int nt = blockIdx.x;
  int t = threadIdx.x, lane = t & 63, w = t >> 6;
  int wm = w >> 1, wn = w & 1;
  int fr = lane & 15, quad = lane >> 4, key = fr & 7;
  int ms = nt >> 7;
  const float* Wsrc = ms ? WB : WA;
  int col0 = (nt & 127) * 128;
  int bn = t & 127, kg = t >> 7;
  const float* bw = Wsrc + col0 + bn;
  unsigned short* bd0 = &Bs[bn * 64 + (((kg * 2) ^ (bn & 7)) * 8)];
  unsigned short* bd1 = &Bs[bn * 64 + (((kg * 2 + 1) ^ (bn & 7)) * 8)];

  floatx4 zero4 = {0.f, 0.f, 0.f, 0.f};
  floatx4 acc[4][4];
#pragma unroll
  for (int i = 0; i < 4; ++i)
#pragma unroll
    for (int j = 0; j < 4; ++j) acc[i][j] = zero4;

  for (int kb = 0; kb < 8; ++kb) {
    __syncthreads();
    const unsigned short* asrc = z_t + (size_t)kb * 16384 + t * 8;
    gl16(asrc, &As[t * 8]);
    gl16(asrc + 4096, &As[t * 8 + 4096]);
    gl16(asrc + 8192, &As[t * 8 + 8192]);
    gl16(asrc + 12288, &As[t * 8 + 12288]);
    const float* bk = bw + (size_t)(kb * 64 + kg * 16) * NBIG;
    float v[16];
#pragma unroll
    for (int kr = 0; kr < 16; ++kr) v[kr] = bk[(size_t)kr * NBIG];
    union { short8 s; unsigned u[4]; } q0, q1;
#pragma unroll
    for (int q = 0; q < 4; ++q) {
      q0.u[q] = pk_bf16(v[2 * q], v[2 * q + 1]);
      q1.u[q] = pk_bf16(v[8 + 2 * q], v[9 + 2 * q]);
    }
    *(short8*)bd0 = q0.s;
    *(short8*)bd1 = q1.s;
    __syncthreads();
#pragma unroll
    for (int ks2 = 0; ks2 < 2; ++ks2) {
      int cof = ((ks2 * 4 + quad) ^ key) * 8;
      short8 bf0 = *(const short8*)&Bs[(wn * 64 + fr) * 64 + cof];
      short8 bf1 = *(const short8*)&Bs[(wn * 64 + 16 + fr) * 64 + cof];
      short8 bf2 = *(const short8*)&Bs[(wn * 64 + 32 + fr) * 64 + cof];
      short8 bf3 = *(const short8*)&Bs[(wn * 64 + 48 + fr) * 64 + cof];
#pragma unroll
      for (int rt = 0; rt < 4; ++rt) {
        short8 af = *(const short8*)&As[(wm * 64 + rt * 16 + fr) * 64 + cof];
        acc[rt][0] = __builtin_amdgcn_mfma_f32_16x16x32_bf16(af, bf0, acc[rt][0], 0, 0, 0);
        acc[rt][1] = __builtin_amdgcn_mfma_f32_16x16x32_bf16(af, bf1, acc[rt][1], 0, 0, 0);
        acc[rt][2] = __builtin_amdgcn_mfma_f32_16x16x32_bf16(af, bf2, acc[rt][2], 0, 0, 0);
        acc[rt][3] = __builtin_amdgcn_mfma_f32_16x16x32_bf16(af, bf3, acc[rt][3], 0, 0, 0);
      }
    }
  }
  const float* bias = ms ? bB : bA;
  float* obase = out + (size_t)ms * 4194304;
#pragma unroll
  for (int nj = 0; nj < 4; ++nj) {
    int nn = col0 + wn * 64 + nj * 16 + fr;
    float bv = bias[nn];
#pragma unroll
    for (int rt = 0; rt < 4; ++rt) {
#pragma unroll
      for (int i2 = 0; i2 < 4; ++i2) {
        int m = wm * 64 + rt * 16 + quad * 4 + i2;
        obase[(size_t)m * NBIG + nn] = acc[rt][nj][i2] + bv;
      }
    }
  }
}

extern "C" void kernel_launch(void* const* d_in, const int* in_sizes, int n_in,
                              void* d_out, int out_size, void* d_ws, size_t ws_size,
                              hipStream_t stream) {
  const float* s = (const float*)d_in[0];
  const float* Wg1 = (const float*)d_in[1];
  const float* bg1 = (const float*)d_in[2];
  const float* Wg2 = (const float*)d_in[3];
  const float* bg2 = (const float*)d_in[4];
  const float* W1 = (const float*)d_in[5];
  const float* b1 = (const float*)d_in[6];
  const float* W2 = (const float*)d_in[7];
  const float* b2 = (const float*)d_in[8];
  const float* WA = (const float*)d_in[9];
  const float* bA = (const float*)d_in[10];
  const float* WB = (const float*)d_in[11];
  const float* bB = (const float*)d_in[12];
  float* out = (float*)d_out;

  char* ws = (char*)d_ws;
  float* g1 = (float*)(ws);                                 // 64 KB
  float* logits = (float*)(ws + 65536);                     // 512 B
  float* base = (float*)(ws + 131072);                      // 1 MB -> ends 1179648
  float* eo2 = (float*)(ws + 1179648);                      // 16.78 MB -> 17956864
  unsigned short* z_t = (unsigned short*)(ws + 17956864);   // 256 KB -> 18219008
  unsigned short* W2t = (unsigned short*)(ws + 18219008);   // 33.55 MB -> 51773440

  k_fusedA<<<4368, 256, 0, stream>>>(s, Wg1, bg1, W1, b1, W2, g1, base, W2t);
  k_fusedB<<<272, 512, 0, stream>>>(base, W1, W2t, g1, Wg2, bg2, eo2, logits);
  k_mix<<<dim3(32, 4), 256, 0, stream>>>(eo2, logits, b2, z_t);
  k_lora2<<<256, 512, 0, stream>>>(z_t, WA, WB, bA, bB, out);
}